// Round 1
// baseline (1497.488 us; speedup 1.0000x reference)
//
#include <hip/hip_runtime.h>

// GCN layer: out = A_norm @ (h @ W^T + b), A_norm = D^-1/2 (A + I) D^-1/2
// Inputs: h [N,128] f32, W [128,128] f32, b [128] f32, edges [2,E] int32
// Output: [N,128] f32
// ws layout: deg (N floats, padded to 512-elem boundary) | h_lin (N*128 floats)

#define IN_DIM 128
#define OUT_DIM 128

__global__ __launch_bounds__(256) void k_init_deg(float* __restrict__ deg, int n) {
    int i = blockIdx.x * 256 + threadIdx.x;
    if (i < n) deg[i] = 1.0f;  // self loop
}

__global__ __launch_bounds__(256) void k_count_deg(const int* __restrict__ dst,
                                                   float* __restrict__ deg, int E) {
    int e = blockIdx.x * 256 + threadIdx.x;
    if (e < E) atomicAdd(&deg[dst[e]], 1.0f);
}

// h_lin = h @ W^T + b.  32 rows/block, 256 threads, each thread 4 rows x 4 cols.
// W staged transposed [k][c] in LDS (stride 132 floats: float4-aligned, kills
// the 128-stride bank degeneracy) in 4 chunks of k=32 to keep LDS at 33.8KB.
__global__ __launch_bounds__(256) void k_linear(const float* __restrict__ h,
                                                const float* __restrict__ W,
                                                const float* __restrict__ b,
                                                float* __restrict__ out, int n) {
    __shared__ float sH[32 * 132];   // [r][k], stride 132
    __shared__ float sWt[32 * 132];  // [kk][c], stride 132, one k-chunk

    const int tid = threadIdx.x;
    const int tx = tid & 31;        // col group: cols 4*tx .. 4*tx+3
    const int ty = tid >> 5;        // row group: rows 4*ty .. 4*ty+3
    const int row0 = blockIdx.x * 32;
    const int r0 = ty * 4;
    const int c0 = tx * 4;

    // stage h tile (32 rows x 128 k) as float4
    {
        const float4* h4 = (const float4*)h;
        float4* sH4 = (float4*)sH;
        for (int t = tid; t < 32 * 32; t += 256) {
            int r = t >> 5, k4 = t & 31;
            int row = row0 + r;
            float4 v = make_float4(0.f, 0.f, 0.f, 0.f);
            if (row < n) v = h4[row * 32 + k4];
            sH4[r * 33 + k4] = v;  // stride 33 float4 = 132 floats
        }
    }

    float acc[4][4];
#pragma unroll
    for (int i = 0; i < 4; ++i)
#pragma unroll
        for (int j = 0; j < 4; ++j) acc[i][j] = 0.f;

    const float4* W4 = (const float4*)W;
    for (int kb = 0; kb < 4; ++kb) {
        __syncthreads();  // guard prior compute (and sH stores on first iter)
        // stage W chunk transposed: sWt[kk][c] = W[c][kb*32+kk]
        for (int t = tid; t < 1024; t += 256) {  // 1024 float4 = 4096 floats
            int c = t >> 3, kk4 = t & 7;
            float4 w = W4[c * 32 + kb * 8 + kk4];
            sWt[(kk4 * 4 + 0) * 132 + c] = w.x;
            sWt[(kk4 * 4 + 1) * 132 + c] = w.y;
            sWt[(kk4 * 4 + 2) * 132 + c] = w.z;
            sWt[(kk4 * 4 + 3) * 132 + c] = w.w;
        }
        __syncthreads();

        const float4* sWt4 = (const float4*)sWt;
#pragma unroll 8
        for (int kk = 0; kk < 32; ++kk) {
            float4 w = sWt4[kk * 33 + tx];  // contiguous 512B across wave
            int k = kb * 32 + kk;
            float h0 = sH[(r0 + 0) * 132 + k];
            float h1 = sH[(r0 + 1) * 132 + k];
            float h2 = sH[(r0 + 2) * 132 + k];
            float h3 = sH[(r0 + 3) * 132 + k];
            acc[0][0] += h0 * w.x; acc[0][1] += h0 * w.y; acc[0][2] += h0 * w.z; acc[0][3] += h0 * w.w;
            acc[1][0] += h1 * w.x; acc[1][1] += h1 * w.y; acc[1][2] += h1 * w.z; acc[1][3] += h1 * w.w;
            acc[2][0] += h2 * w.x; acc[2][1] += h2 * w.y; acc[2][2] += h2 * w.z; acc[2][3] += h2 * w.w;
            acc[3][0] += h3 * w.x; acc[3][1] += h3 * w.y; acc[3][2] += h3 * w.z; acc[3][3] += h3 * w.w;
        }
    }

    float4 bv = ((const float4*)b)[tx];
    float4* out4 = (float4*)out;
#pragma unroll
    for (int i = 0; i < 4; ++i) {
        int row = row0 + r0 + i;
        if (row < n) {
            float4 o;
            o.x = acc[i][0] + bv.x;
            o.y = acc[i][1] + bv.y;
            o.z = acc[i][2] + bv.z;
            o.w = acc[i][3] + bv.w;
            out4[row * 32 + tx] = o;
        }
    }
}

// Self-loop term: out[i] = h_lin[i] / deg[i]  (rsqrt(d*d)=1/d). Plain store
// (initializes out; d_out is poisoned before each launch).
__global__ __launch_bounds__(256) void k_self(const float* __restrict__ hl,
                                              const float* __restrict__ deg,
                                              float* __restrict__ out, int n) {
    int idx = blockIdx.x * 256 + threadIdx.x;
    if (idx >= n * 32) return;
    int i = idx >> 5, c4 = idx & 31;
    float s = 1.0f / deg[i];
    float4 v = ((const float4*)hl)[i * 32 + c4];
    v.x *= s; v.y *= s; v.z *= s; v.w *= s;
    ((float4*)out)[i * 32 + c4] = v;
}

// Edge scatter: out[dst] += h_lin[src] * rsqrt(deg[src]*deg[dst])
// One thread per (edge, 4 channels): float4 gather + 4 f32 atomics.
__global__ __launch_bounds__(256) void k_edges(const int* __restrict__ ed,
                                               const float* __restrict__ hl,
                                               const float* __restrict__ deg,
                                               float* __restrict__ out, int E) {
    int idx = blockIdx.x * 256 + threadIdx.x;
    int e = idx >> 5;
    if (e >= E) return;
    int c4 = idx & 31;
    int src = ed[e];
    int dst = ed[E + e];
    float w = rsqrtf(deg[src] * deg[dst]);
    float4 v = ((const float4*)hl)[src * 32 + c4];
    float* o = out + dst * 128 + c4 * 4;
    atomicAdd(o + 0, v.x * w);
    atomicAdd(o + 1, v.y * w);
    atomicAdd(o + 2, v.z * w);
    atomicAdd(o + 3, v.w * w);
}

extern "C" void kernel_launch(void* const* d_in, const int* in_sizes, int n_in,
                              void* d_out, int out_size, void* d_ws, size_t ws_size,
                              hipStream_t stream) {
    const float* h = (const float*)d_in[0];
    const float* W = (const float*)d_in[1];
    const float* b = (const float*)d_in[2];
    const int* edges = (const int*)d_in[3];

    const int n = in_sizes[0] / IN_DIM;   // 50000
    const int E = in_sizes[3] / 2;        // 800000

    float* deg = (float*)d_ws;
    size_t deg_pad = ((size_t)n + 511) & ~(size_t)511;
    float* hl = (float*)d_ws + deg_pad;   // [n,128]

    float* out = (float*)d_out;

    k_init_deg<<<(n + 255) / 256, 256, 0, stream>>>(deg, n);
    k_count_deg<<<(E + 255) / 256, 256, 0, stream>>>(edges + E, deg, E);
    k_linear<<<(n + 31) / 32, 256, 0, stream>>>(h, W, b, hl, n);
    k_self<<<(n * 32 + 255) / 256, 256, 0, stream>>>(hl, deg, out, n);
    k_edges<<<((long long)E * 32 + 255) / 256, 256, 0, stream>>>(edges, hl, deg, out, E);
}

// Round 2
// 305.094 us; speedup vs baseline: 4.9083x; 4.9083x over previous
//
#include <hip/hip_runtime.h>

// GCN layer: out = A_norm @ (h @ W^T + b), A_norm = D^-1/2 (A + I) D^-1/2
// Inputs: h [N,128] f32, W [128,128] f32, b [128] f32, edges [2,E] int32
// Output: [N,128] f32
//
// R2: replace 102.4M float atomics (R1: 1341us, WRITE_SIZE=1.6GB) with
// dst-CSR build (800k int atomics) + one-wave-per-node gather-reduce.
// ws layout: hl[N*128] | cnt[n] | off[n+1] | cursor[n] | degf[n] | csr_src[E] | csr_w[E]

#define IN_DIM 128
#define OUT_DIM 128

__global__ __launch_bounds__(256) void k_zero_cnt(int* __restrict__ cnt, int n) {
    int i = blockIdx.x * 256 + threadIdx.x;
    if (i < n) cnt[i] = 0;
}

__global__ __launch_bounds__(256) void k_count(const int* __restrict__ dst,
                                               int* __restrict__ cnt, int E) {
    int e = blockIdx.x * 256 + threadIdx.x;
    if (e < E) atomicAdd(&cnt[dst[e]], 1);
}

// Single-block exclusive scan over n counts (wave-shuffle scan, 16 waves).
// Also emits cursor (= off copy) and degf (= cnt+1, self loop included).
__global__ __launch_bounds__(1024) void k_scan(const int* __restrict__ cnt,
                                               int* __restrict__ off,
                                               int* __restrict__ cursor,
                                               float* __restrict__ degf, int n) {
    __shared__ int wsum[16];
    __shared__ int sbase;
    const int tid = threadIdx.x;
    const int lane = tid & 63;
    const int wv = tid >> 6;
    if (tid == 0) sbase = 0;
    __syncthreads();
    for (int base = 0; base < n; base += 1024) {
        int i = base + tid;
        int v = (i < n) ? cnt[i] : 0;
        int x = v;  // inclusive scan within wave
#pragma unroll
        for (int d = 1; d < 64; d <<= 1) {
            int t = __shfl_up(x, d, 64);
            if (lane >= d) x += t;
        }
        if (lane == 63) wsum[wv] = x;
        __syncthreads();
        if (wv == 0) {  // wave 0 scans the 16 wave sums (inclusive)
            int y = (lane < 16) ? wsum[lane] : 0;
#pragma unroll
            for (int d = 1; d < 16; d <<= 1) {
                int t = __shfl_up(y, d, 64);
                if (lane >= d) y += t;
            }
            if (lane < 16) wsum[lane] = y;
        }
        __syncthreads();
        int waveoff = (wv == 0) ? 0 : wsum[wv - 1];
        int b = sbase;
        int excl = b + waveoff + x - v;
        if (i < n) {
            off[i] = excl;
            cursor[i] = excl;
            degf[i] = (float)(v + 1);
        }
        int chunk_total = wsum[15];
        __syncthreads();
        if (tid == 0) sbase = b + chunk_total;
        __syncthreads();
    }
    if (tid == 0) off[n] = sbase;
}

// Scatter edges into CSR buckets; precompute symmetric-norm weight.
__global__ __launch_bounds__(256) void k_fill(const int* __restrict__ ed,
                                              const float* __restrict__ degf,
                                              int* __restrict__ cursor,
                                              int* __restrict__ csr_src,
                                              float* __restrict__ csr_w, int E) {
    int e = blockIdx.x * 256 + threadIdx.x;
    if (e >= E) return;
    int s = ed[e];
    int d = ed[E + e];
    int pos = atomicAdd(&cursor[d], 1);
    csr_src[pos] = s;
    csr_w[pos] = rsqrtf(degf[s] * degf[d]);
}

// h_lin = h @ W^T + b.  32 rows/block, 256 threads, 4x4 register tile.
__global__ __launch_bounds__(256) void k_linear(const float* __restrict__ h,
                                                const float* __restrict__ W,
                                                const float* __restrict__ b,
                                                float* __restrict__ out, int n) {
    __shared__ float sH[32 * 132];   // [r][k], stride 132
    __shared__ float sWt[32 * 132];  // [kk][c], stride 132, one k-chunk

    const int tid = threadIdx.x;
    const int tx = tid & 31;
    const int ty = tid >> 5;
    const int row0 = blockIdx.x * 32;
    const int r0 = ty * 4;

    {
        const float4* h4 = (const float4*)h;
        float4* sH4 = (float4*)sH;
        for (int t = tid; t < 32 * 32; t += 256) {
            int r = t >> 5, k4 = t & 31;
            int row = row0 + r;
            float4 v = make_float4(0.f, 0.f, 0.f, 0.f);
            if (row < n) v = h4[row * 32 + k4];
            sH4[r * 33 + k4] = v;
        }
    }

    float acc[4][4];
#pragma unroll
    for (int i = 0; i < 4; ++i)
#pragma unroll
        for (int j = 0; j < 4; ++j) acc[i][j] = 0.f;

    const float4* W4 = (const float4*)W;
    for (int kb = 0; kb < 4; ++kb) {
        __syncthreads();
        for (int t = tid; t < 1024; t += 256) {
            int c = t >> 3, kk4 = t & 7;
            float4 w = W4[c * 32 + kb * 8 + kk4];
            sWt[(kk4 * 4 + 0) * 132 + c] = w.x;
            sWt[(kk4 * 4 + 1) * 132 + c] = w.y;
            sWt[(kk4 * 4 + 2) * 132 + c] = w.z;
            sWt[(kk4 * 4 + 3) * 132 + c] = w.w;
        }
        __syncthreads();

        const float4* sWt4 = (const float4*)sWt;
#pragma unroll 8
        for (int kk = 0; kk < 32; ++kk) {
            float4 w = sWt4[kk * 33 + tx];
            int k = kb * 32 + kk;
            float h0 = sH[(r0 + 0) * 132 + k];
            float h1 = sH[(r0 + 1) * 132 + k];
            float h2 = sH[(r0 + 2) * 132 + k];
            float h3 = sH[(r0 + 3) * 132 + k];
            acc[0][0] += h0 * w.x; acc[0][1] += h0 * w.y; acc[0][2] += h0 * w.z; acc[0][3] += h0 * w.w;
            acc[1][0] += h1 * w.x; acc[1][1] += h1 * w.y; acc[1][2] += h1 * w.z; acc[1][3] += h1 * w.w;
            acc[2][0] += h2 * w.x; acc[2][1] += h2 * w.y; acc[2][2] += h2 * w.z; acc[2][3] += h2 * w.w;
            acc[3][0] += h3 * w.x; acc[3][1] += h3 * w.y; acc[3][2] += h3 * w.z; acc[3][3] += h3 * w.w;
        }
    }

    float4 bv = ((const float4*)b)[tx];
    float4* out4 = (float4*)out;
#pragma unroll
    for (int i = 0; i < 4; ++i) {
        int row = row0 + r0 + i;
        if (row < n) {
            float4 o;
            o.x = acc[i][0] + bv.x;
            o.y = acc[i][1] + bv.y;
            o.z = acc[i][2] + bv.z;
            o.w = acc[i][3] + bv.w;
            out4[row * 32 + tx] = o;
        }
    }
}

// One wave per node: lane holds 2 channels (float2). Accumulator starts with
// the fused self-loop term hl[node]/deg[node]; loop CSR edges (unroll 2).
__global__ __launch_bounds__(256) void k_agg(const int* __restrict__ off,
                                             const int* __restrict__ csr_src,
                                             const float* __restrict__ csr_w,
                                             const float* __restrict__ degf,
                                             const float* __restrict__ hl,
                                             float* __restrict__ out, int n) {
    int node = blockIdx.x * 4 + (threadIdx.x >> 6);
    if (node >= n) return;
    int lane = threadIdx.x & 63;
    const float2* hl2 = (const float2*)hl;
    int beg = off[node], end = off[node + 1];
    float dinv = 1.0f / degf[node];
    float2 a = hl2[(size_t)node * 64 + lane];
    float2 acc;
    acc.x = a.x * dinv;
    acc.y = a.y * dinv;
    int e = beg;
    for (; e + 2 <= end; e += 2) {
        int s0 = csr_src[e], s1 = csr_src[e + 1];
        float w0 = csr_w[e], w1 = csr_w[e + 1];
        float2 v0 = hl2[(size_t)s0 * 64 + lane];
        float2 v1 = hl2[(size_t)s1 * 64 + lane];
        acc.x += w0 * v0.x; acc.y += w0 * v0.y;
        acc.x += w1 * v1.x; acc.y += w1 * v1.y;
    }
    if (e < end) {
        int s0 = csr_src[e];
        float w0 = csr_w[e];
        float2 v0 = hl2[(size_t)s0 * 64 + lane];
        acc.x += w0 * v0.x;
        acc.y += w0 * v0.y;
    }
    ((float2*)out)[(size_t)node * 64 + lane] = acc;
}

extern "C" void kernel_launch(void* const* d_in, const int* in_sizes, int n_in,
                              void* d_out, int out_size, void* d_ws, size_t ws_size,
                              hipStream_t stream) {
    const float* h = (const float*)d_in[0];
    const float* W = (const float*)d_in[1];
    const float* b = (const float*)d_in[2];
    const int* edges = (const int*)d_in[3];

    const int n = in_sizes[0] / IN_DIM;   // 50000
    const int E = in_sizes[3] / 2;        // 800000

    // workspace carve-up (each region padded to 512 elems = 2KB)
    size_t o = 0;
    auto carve = [&](size_t elems) {
        size_t cur = o;
        o += (elems + 511) & ~(size_t)511;
        return cur;
    };
    float* ws = (float*)d_ws;
    float* hl      = ws + carve((size_t)n * 128);
    int*   cnt     = (int*)(ws + carve(n));
    int*   off     = (int*)(ws + carve(n + 1));
    int*   cursor  = (int*)(ws + carve(n));
    float* degf    = ws + carve(n);
    int*   csr_src = (int*)(ws + carve(E));
    float* csr_w   = ws + carve(E);

    float* out = (float*)d_out;

    k_zero_cnt<<<(n + 255) / 256, 256, 0, stream>>>(cnt, n);
    k_count<<<(E + 255) / 256, 256, 0, stream>>>(edges + E, cnt, E);
    k_scan<<<1, 1024, 0, stream>>>(cnt, off, cursor, degf, n);
    k_fill<<<(E + 255) / 256, 256, 0, stream>>>(edges, degf, cursor, csr_src, csr_w, E);
    k_linear<<<(n + 31) / 32, 256, 0, stream>>>(h, W, b, hl, n);
    k_agg<<<(n + 3) / 4, 256, 0, stream>>>(off, csr_src, csr_w, degf, hl, out, n);
}

// Round 4
// 232.656 us; speedup vs baseline: 6.4365x; 1.3114x over previous
//
#include <hip/hip_runtime.h>

// GCN layer: out = A_norm @ (h @ W^T + b), A_norm = D^-1/2 (A + I) D^-1/2
// Inputs: h [N,128] f32, W [128,128] f32, b [128] f32, edges [2,E] int32
// Output: [N,128] f32
//
// R3/R4: (1) multi-block scan (R2's single-block scan serialized 1 CU),
//        (2) hl stored bf16 -> gather stream 410->205 MB (f32 accumulate),
//        (3) CSR packed int2(src, w) -> one 8B scattered store per edge.
// R4 fixes R3's compile error (hlb pointer-type cast at k_agg launch).

#define IN_DIM 128
#define OUT_DIM 128

__device__ __forceinline__ unsigned short f2bf(float f) {
    unsigned u = __float_as_uint(f);
    u += 0x7fffu + ((u >> 16) & 1u);  // round-nearest-even
    return (unsigned short)(u >> 16);
}

__global__ __launch_bounds__(256) void k_zero_cnt(int* __restrict__ cnt, int n) {
    int i = blockIdx.x * 256 + threadIdx.x;
    if (i < n) cnt[i] = 0;
}

__global__ __launch_bounds__(256) void k_count(const int* __restrict__ dst,
                                               int* __restrict__ cnt, int E) {
    int e = blockIdx.x * 256 + threadIdx.x;
    if (e < E) atomicAdd(&cnt[dst[e]], 1);
}

// Pass 1: per-block (1024) exclusive scan of cnt -> off (block-local), block sum -> bsum.
__global__ __launch_bounds__(1024) void k_scan1(const int* __restrict__ cnt,
                                                int* __restrict__ off,
                                                int* __restrict__ bsum, int n) {
    __shared__ int wsum[16];
    const int tid = threadIdx.x;
    const int lane = tid & 63;
    const int wv = tid >> 6;
    int i = blockIdx.x * 1024 + tid;
    int v = (i < n) ? cnt[i] : 0;
    int x = v;
#pragma unroll
    for (int d = 1; d < 64; d <<= 1) {
        int t = __shfl_up(x, d, 64);
        if (lane >= d) x += t;
    }
    if (lane == 63) wsum[wv] = x;
    __syncthreads();
    if (wv == 0) {
        int y = (lane < 16) ? wsum[lane] : 0;
#pragma unroll
        for (int d = 1; d < 16; d <<= 1) {
            int t = __shfl_up(y, d, 64);
            if (lane >= d) y += t;
        }
        if (lane < 16) wsum[lane] = y;
    }
    __syncthreads();
    int waveoff = (wv == 0) ? 0 : wsum[wv - 1];
    if (i < n) off[i] = waveoff + x - v;
    if (tid == 0) bsum[blockIdx.x] = wsum[15];
}

// Pass 2: one wave scans nb (<=64) block sums -> bbase (exclusive); off[n] = total.
__global__ __launch_bounds__(64) void k_scan2(const int* __restrict__ bsum,
                                              int* __restrict__ bbase,
                                              int* __restrict__ off, int nb, int n) {
    int lane = threadIdx.x;
    int v = (lane < nb) ? bsum[lane] : 0;
    int x = v;
#pragma unroll
    for (int d = 1; d < 64; d <<= 1) {
        int t = __shfl_up(x, d, 64);
        if (lane >= d) x += t;
    }
    if (lane < nb) bbase[lane] = x - v;
    if (lane == nb - 1) off[n] = x;
}

// Pass 3: add block base; emit cursor copy and float degree (incl self loop).
__global__ __launch_bounds__(1024) void k_scan3(const int* __restrict__ cnt,
                                                const int* __restrict__ bbase,
                                                int* __restrict__ off,
                                                int* __restrict__ cursor,
                                                float* __restrict__ degf, int n) {
    int i = blockIdx.x * 1024 + threadIdx.x;
    if (i >= n) return;
    int o = off[i] + bbase[blockIdx.x];
    off[i] = o;
    cursor[i] = o;
    degf[i] = (float)(cnt[i] + 1);
}

// Scatter edges into CSR buckets; pack (src, weight) into one int2.
__global__ __launch_bounds__(256) void k_fill(const int* __restrict__ ed,
                                              const float* __restrict__ degf,
                                              int* __restrict__ cursor,
                                              int2* __restrict__ csr, int E) {
    int e = blockIdx.x * 256 + threadIdx.x;
    if (e >= E) return;
    int s = ed[e];
    int d = ed[E + e];
    int pos = atomicAdd(&cursor[d], 1);
    int2 pk;
    pk.x = s;
    pk.y = __float_as_int(rsqrtf(degf[s] * degf[d]));
    csr[pos] = pk;
}

// h_lin = h @ W^T + b, output bf16.  32 rows/block, 256 threads, 4x4 reg tile.
__global__ __launch_bounds__(256) void k_linear(const float* __restrict__ h,
                                                const float* __restrict__ W,
                                                const float* __restrict__ b,
                                                unsigned short* __restrict__ hlb, int n) {
    __shared__ float sH[32 * 132];   // [r][k], stride 132
    __shared__ float sWt[32 * 132];  // [kk][c], stride 132, one k-chunk

    const int tid = threadIdx.x;
    const int tx = tid & 31;
    const int ty = tid >> 5;
    const int row0 = blockIdx.x * 32;
    const int r0 = ty * 4;

    {
        const float4* h4 = (const float4*)h;
        float4* sH4 = (float4*)sH;
        for (int t = tid; t < 32 * 32; t += 256) {
            int r = t >> 5, k4 = t & 31;
            int row = row0 + r;
            float4 v = make_float4(0.f, 0.f, 0.f, 0.f);
            if (row < n) v = h4[row * 32 + k4];
            sH4[r * 33 + k4] = v;
        }
    }

    float acc[4][4];
#pragma unroll
    for (int i = 0; i < 4; ++i)
#pragma unroll
        for (int j = 0; j < 4; ++j) acc[i][j] = 0.f;

    const float4* W4 = (const float4*)W;
    for (int kb = 0; kb < 4; ++kb) {
        __syncthreads();
        for (int t = tid; t < 1024; t += 256) {
            int c = t >> 3, kk4 = t & 7;
            float4 w = W4[c * 32 + kb * 8 + kk4];
            sWt[(kk4 * 4 + 0) * 132 + c] = w.x;
            sWt[(kk4 * 4 + 1) * 132 + c] = w.y;
            sWt[(kk4 * 4 + 2) * 132 + c] = w.z;
            sWt[(kk4 * 4 + 3) * 132 + c] = w.w;
        }
        __syncthreads();

        const float4* sWt4 = (const float4*)sWt;
#pragma unroll 8
        for (int kk = 0; kk < 32; ++kk) {
            float4 w = sWt4[kk * 33 + tx];
            int k = kb * 32 + kk;
            float h0 = sH[(r0 + 0) * 132 + k];
            float h1 = sH[(r0 + 1) * 132 + k];
            float h2 = sH[(r0 + 2) * 132 + k];
            float h3 = sH[(r0 + 3) * 132 + k];
            acc[0][0] += h0 * w.x; acc[0][1] += h0 * w.y; acc[0][2] += h0 * w.z; acc[0][3] += h0 * w.w;
            acc[1][0] += h1 * w.x; acc[1][1] += h1 * w.y; acc[1][2] += h1 * w.z; acc[1][3] += h1 * w.w;
            acc[2][0] += h2 * w.x; acc[2][1] += h2 * w.y; acc[2][2] += h2 * w.z; acc[2][3] += h2 * w.w;
            acc[3][0] += h3 * w.x; acc[3][1] += h3 * w.y; acc[3][2] += h3 * w.z; acc[3][3] += h3 * w.w;
        }
    }

    float4 bv = ((const float4*)b)[tx];
    ushort4* out4 = (ushort4*)hlb;
#pragma unroll
    for (int i = 0; i < 4; ++i) {
        int row = row0 + r0 + i;
        if (row < n) {
            ushort4 o;
            o.x = f2bf(acc[i][0] + bv.x);
            o.y = f2bf(acc[i][1] + bv.y);
            o.z = f2bf(acc[i][2] + bv.z);
            o.w = f2bf(acc[i][3] + bv.w);
            out4[row * 32 + tx] = o;
        }
    }
}

// One wave per node; lane = 2 channels packed in one uint (2x bf16).
// Accumulate f32; self-loop term fused; unroll 4 for memory-level parallelism.
__global__ __launch_bounds__(256) void k_agg(const int* __restrict__ off,
                                             const int2* __restrict__ csr,
                                             const float* __restrict__ degf,
                                             const unsigned* __restrict__ hlb,
                                             float* __restrict__ out, int n) {
    int node = blockIdx.x * 4 + (threadIdx.x >> 6);
    if (node >= n) return;
    int lane = threadIdx.x & 63;
    int beg = off[node], end = off[node + 1];
    float dinv = 1.0f / degf[node];

    unsigned u = hlb[(size_t)node * 64 + lane];
    float2 acc;
    acc.x = __uint_as_float(u << 16) * dinv;
    acc.y = __uint_as_float(u & 0xffff0000u) * dinv;

    int e = beg;
    for (; e + 4 <= end; e += 4) {
        int2 c0 = csr[e + 0], c1 = csr[e + 1], c2 = csr[e + 2], c3 = csr[e + 3];
        unsigned v0 = hlb[(size_t)c0.x * 64 + lane];
        unsigned v1 = hlb[(size_t)c1.x * 64 + lane];
        unsigned v2 = hlb[(size_t)c2.x * 64 + lane];
        unsigned v3 = hlb[(size_t)c3.x * 64 + lane];
        float w0 = __int_as_float(c0.y), w1 = __int_as_float(c1.y);
        float w2 = __int_as_float(c2.y), w3 = __int_as_float(c3.y);
        acc.x += w0 * __uint_as_float(v0 << 16);
        acc.y += w0 * __uint_as_float(v0 & 0xffff0000u);
        acc.x += w1 * __uint_as_float(v1 << 16);
        acc.y += w1 * __uint_as_float(v1 & 0xffff0000u);
        acc.x += w2 * __uint_as_float(v2 << 16);
        acc.y += w2 * __uint_as_float(v2 & 0xffff0000u);
        acc.x += w3 * __uint_as_float(v3 << 16);
        acc.y += w3 * __uint_as_float(v3 & 0xffff0000u);
    }
    for (; e < end; ++e) {
        int2 c = csr[e];
        unsigned v = hlb[(size_t)c.x * 64 + lane];
        float w = __int_as_float(c.y);
        acc.x += w * __uint_as_float(v << 16);
        acc.y += w * __uint_as_float(v & 0xffff0000u);
    }
    ((float2*)out)[(size_t)node * 64 + lane] = acc;
}

extern "C" void kernel_launch(void* const* d_in, const int* in_sizes, int n_in,
                              void* d_out, int out_size, void* d_ws, size_t ws_size,
                              hipStream_t stream) {
    const float* h = (const float*)d_in[0];
    const float* W = (const float*)d_in[1];
    const float* b = (const float*)d_in[2];
    const int* edges = (const int*)d_in[3];

    const int n = in_sizes[0] / IN_DIM;   // 50000
    const int E = in_sizes[3] / 2;        // 800000
    const int nb = (n + 1023) / 1024;     // 49 scan blocks

    // workspace carve-up (float units, each region 2KB-aligned)
    size_t o = 0;
    auto carve = [&](size_t elems) {
        size_t cur = o;
        o += (elems + 511) & ~(size_t)511;
        return cur;
    };
    float* ws = (float*)d_ws;
    unsigned short* hlb = (unsigned short*)(ws + carve((size_t)n * 64));  // n*128 bf16
    int*   cnt     = (int*)(ws + carve(n));
    int*   off     = (int*)(ws + carve(n + 1));
    int*   cursor  = (int*)(ws + carve(n));
    float* degf    = ws + carve(n);
    int*   bsum    = (int*)(ws + carve(64));
    int*   bbase   = (int*)(ws + carve(64));
    int2*  csr     = (int2*)(ws + carve((size_t)E * 2));

    float* out = (float*)d_out;

    k_linear<<<(n + 31) / 32, 256, 0, stream>>>(h, W, b, hlb, n);
    k_zero_cnt<<<(n + 255) / 256, 256, 0, stream>>>(cnt, n);
    k_count<<<(E + 255) / 256, 256, 0, stream>>>(edges + E, cnt, E);
    k_scan1<<<nb, 1024, 0, stream>>>(cnt, off, bsum, n);
    k_scan2<<<1, 64, 0, stream>>>(bsum, bbase, off, nb, n);
    k_scan3<<<nb, 1024, 0, stream>>>(cnt, bbase, off, cursor, degf, n);
    k_fill<<<(E + 255) / 256, 256, 0, stream>>>(edges, degf, cursor, csr, E);
    k_agg<<<(n + 3) / 4, 256, 0, stream>>>(off, csr, degf,
                                           (const unsigned*)hlb, out, n);
}

// Round 5
// 219.058 us; speedup vs baseline: 6.8360x; 1.0621x over previous
//
#include <hip/hip_runtime.h>

// GCN layer: out = A_norm @ (h @ W^T + b), A_norm = D^-1/2 (A + I) D^-1/2
// Inputs: h [N,128] f32, W [128,128] f32, b [128] f32, edges [2,E] int32
// Output: [N,128] f32
//
// R5: (1) k_linear -> MFMA bf16 (16x16x32), h/W converted to bf16 in LDS
//         staging; hl was already consumed as bf16 downstream.
//     (2) k_agg: csr loads paired as int4, unroll 8 for MLP.
// Pipeline: linear | zero+count+scan(3)+fill (CSR by dst) | gather-reduce.

#define IN_DIM 128
#define OUT_DIM 128

typedef short bf16x8 __attribute__((ext_vector_type(8)));
typedef float f32x4 __attribute__((ext_vector_type(4)));

__device__ __forceinline__ unsigned short f2bf(float f) {
    unsigned u = __float_as_uint(f);
    u += 0x7fffu + ((u >> 16) & 1u);  // round-nearest-even
    return (unsigned short)(u >> 16);
}
__device__ __forceinline__ float bf2f(unsigned short s) {
    return __uint_as_float(((unsigned)s) << 16);
}

__global__ __launch_bounds__(256) void k_zero_cnt(int* __restrict__ cnt, int n) {
    int i = blockIdx.x * 256 + threadIdx.x;
    if (i < n) cnt[i] = 0;
}

__global__ __launch_bounds__(256) void k_count(const int* __restrict__ dst,
                                               int* __restrict__ cnt, int E) {
    int e = blockIdx.x * 256 + threadIdx.x;
    if (e < E) atomicAdd(&cnt[dst[e]], 1);
}

// Pass 1: per-block (1024) exclusive scan of cnt -> off (block-local), block sum -> bsum.
__global__ __launch_bounds__(1024) void k_scan1(const int* __restrict__ cnt,
                                                int* __restrict__ off,
                                                int* __restrict__ bsum, int n) {
    __shared__ int wsum[16];
    const int tid = threadIdx.x;
    const int lane = tid & 63;
    const int wv = tid >> 6;
    int i = blockIdx.x * 1024 + tid;
    int v = (i < n) ? cnt[i] : 0;
    int x = v;
#pragma unroll
    for (int d = 1; d < 64; d <<= 1) {
        int t = __shfl_up(x, d, 64);
        if (lane >= d) x += t;
    }
    if (lane == 63) wsum[wv] = x;
    __syncthreads();
    if (wv == 0) {
        int y = (lane < 16) ? wsum[lane] : 0;
#pragma unroll
        for (int d = 1; d < 16; d <<= 1) {
            int t = __shfl_up(y, d, 64);
            if (lane >= d) y += t;
        }
        if (lane < 16) wsum[lane] = y;
    }
    __syncthreads();
    int waveoff = (wv == 0) ? 0 : wsum[wv - 1];
    if (i < n) off[i] = waveoff + x - v;
    if (tid == 0) bsum[blockIdx.x] = wsum[15];
}

// Pass 2: one wave scans nb (<=64) block sums -> bbase (exclusive); off[n] = total.
__global__ __launch_bounds__(64) void k_scan2(const int* __restrict__ bsum,
                                              int* __restrict__ bbase,
                                              int* __restrict__ off, int nb, int n) {
    int lane = threadIdx.x;
    int v = (lane < nb) ? bsum[lane] : 0;
    int x = v;
#pragma unroll
    for (int d = 1; d < 64; d <<= 1) {
        int t = __shfl_up(x, d, 64);
        if (lane >= d) x += t;
    }
    if (lane < nb) bbase[lane] = x - v;
    if (lane == nb - 1) off[n] = x;
}

// Pass 3: add block base; emit cursor copy and float degree (incl self loop).
__global__ __launch_bounds__(1024) void k_scan3(const int* __restrict__ cnt,
                                                const int* __restrict__ bbase,
                                                int* __restrict__ off,
                                                int* __restrict__ cursor,
                                                float* __restrict__ degf, int n) {
    int i = blockIdx.x * 1024 + threadIdx.x;
    if (i >= n) return;
    int o = off[i] + bbase[blockIdx.x];
    off[i] = o;
    cursor[i] = o;
    degf[i] = (float)(cnt[i] + 1);
}

// Scatter edges into CSR buckets; pack (src, weight) into one int2.
__global__ __launch_bounds__(256) void k_fill(const int* __restrict__ ed,
                                              const float* __restrict__ degf,
                                              int* __restrict__ cursor,
                                              int2* __restrict__ csr, int E) {
    int e = blockIdx.x * 256 + threadIdx.x;
    if (e >= E) return;
    int s = ed[e];
    int d = ed[E + e];
    int pos = atomicAdd(&cursor[d], 1);
    int2 pk;
    pk.x = s;
    pk.y = __float_as_int(rsqrtf(degf[s] * degf[d]));
    csr[pos] = pk;
}

// hl(bf16) = h @ W^T + b via MFMA 16x16x32 bf16.
// Block: 128 rows x 128 cols x K=128, 256 thr (4 waves), wave = 32 rows.
// A frag: h[m=l16][k=quad*8+j]; B frag: W[n=l16][k=quad*8+j] (hl=h@W^T);
// C/D: col=lane&15, row=quad*4+reg (m89-verified mapping).
// LDS rows padded to 136 bf16 (272B = 68 banks -> 16-row stride aliases 2-way = free).
__global__ __launch_bounds__(256) void k_linear(const float* __restrict__ h,
                                                const float* __restrict__ W,
                                                const float* __restrict__ b,
                                                unsigned short* __restrict__ hlb, int n) {
    __shared__ unsigned short sA[128 * 136];  // h tile bf16
    __shared__ unsigned short sB[128 * 136];  // W bf16 (full, [n][k])

    const int tid = threadIdx.x;
    const int lane = tid & 63;
    const int wv = tid >> 6;
    const int quad = lane >> 4;
    const int l16 = lane & 15;
    const int row0 = blockIdx.x * 128;

    // stage h (zero-fill OOB rows) and W, f32 -> bf16
    {
        const float4* h4 = (const float4*)h;
        const float4* W4 = (const float4*)W;
        for (int t = tid; t < 128 * 32; t += 256) {
            int r = t >> 5, c4 = t & 31;
            int row = row0 + r;
            float4 v = make_float4(0.f, 0.f, 0.f, 0.f);
            if (row < n) v = h4[(size_t)row * 32 + c4];
            ushort4 p;
            p.x = f2bf(v.x); p.y = f2bf(v.y); p.z = f2bf(v.z); p.w = f2bf(v.w);
            ((ushort4*)sA)[r * 34 + c4] = p;  // 136/4 = 34
            float4 w = W4[t];                 // t = r*32+c4 covers all of W
            ushort4 q;
            q.x = f2bf(w.x); q.y = f2bf(w.y); q.z = f2bf(w.z); q.w = f2bf(w.w);
            ((ushort4*)sB)[r * 34 + c4] = q;
        }
    }
    __syncthreads();

    f32x4 acc[2][8];
#pragma unroll
    for (int mt = 0; mt < 2; ++mt)
#pragma unroll
        for (int nt = 0; nt < 8; ++nt) acc[mt][nt] = (f32x4){0.f, 0.f, 0.f, 0.f};

    const int koff = quad * 8;  // element offset of this lane's 8-bf16 fragment
#pragma unroll
    for (int kc = 0; kc < 4; ++kc) {
        int kbase = kc * 32 + koff;
        bf16x8 a0 = *(const bf16x8*)(sA + (wv * 32 + 0 + l16) * 136 + kbase);
        bf16x8 a1 = *(const bf16x8*)(sA + (wv * 32 + 16 + l16) * 136 + kbase);
#pragma unroll
        for (int nt = 0; nt < 8; ++nt) {
            bf16x8 bb = *(const bf16x8*)(sB + (nt * 16 + l16) * 136 + kbase);
            acc[0][nt] = __builtin_amdgcn_mfma_f32_16x16x32_bf16(a0, bb, acc[0][nt], 0, 0, 0);
            acc[1][nt] = __builtin_amdgcn_mfma_f32_16x16x32_bf16(a1, bb, acc[1][nt], 0, 0, 0);
        }
    }

    // epilogue: add bias, convert to bf16, store (2B/lane, 16-lane contiguous)
#pragma unroll
    for (int mt = 0; mt < 2; ++mt) {
#pragma unroll
        for (int nt = 0; nt < 8; ++nt) {
            int col = nt * 16 + l16;
            float bias = b[col];
#pragma unroll
            for (int r = 0; r < 4; ++r) {
                int row = row0 + wv * 32 + mt * 16 + quad * 4 + r;
                if (row < n)
                    hlb[(size_t)row * 128 + col] = f2bf(acc[mt][nt][r] + bias);
            }
        }
    }
}

// One wave per node; lane = 2 channels packed in one uint (2x bf16).
// csr loaded as int4 (2 edges / 16B), unroll 8 edges for MLP; f32 accumulate.
__global__ __launch_bounds__(256) void k_agg(const int* __restrict__ off,
                                             const int2* __restrict__ csr,
                                             const float* __restrict__ degf,
                                             const unsigned* __restrict__ hlb,
                                             float* __restrict__ out, int n) {
    int node = blockIdx.x * 4 + (threadIdx.x >> 6);
    if (node >= n) return;
    int lane = threadIdx.x & 63;
    int beg = off[node], end = off[node + 1];
    float dinv = 1.0f / degf[node];

    unsigned u = hlb[(size_t)node * 64 + lane];
    float2 acc;
    acc.x = __uint_as_float(u << 16) * dinv;
    acc.y = __uint_as_float(u & 0xffff0000u) * dinv;

    int e = beg;
    if ((e & 1) && e < end) {  // align to int4 boundary
        int2 c = csr[e];
        unsigned v = hlb[(size_t)c.x * 64 + lane];
        float w = __int_as_float(c.y);
        acc.x += w * __uint_as_float(v << 16);
        acc.y += w * __uint_as_float(v & 0xffff0000u);
        ++e;
    }
    const int4* csr4 = (const int4*)csr;
    // 8-edge unrolled main loop (4 int4 loads + 8 row gathers in flight)
    for (; e + 8 <= end; e += 8) {
        int i4 = e >> 1;
        int4 p0 = csr4[i4 + 0];
        int4 p1 = csr4[i4 + 1];
        int4 p2 = csr4[i4 + 2];
        int4 p3 = csr4[i4 + 3];
        unsigned v0 = hlb[(size_t)p0.x * 64 + lane];
        unsigned v1 = hlb[(size_t)p0.z * 64 + lane];
        unsigned v2 = hlb[(size_t)p1.x * 64 + lane];
        unsigned v3 = hlb[(size_t)p1.z * 64 + lane];
        unsigned v4 = hlb[(size_t)p2.x * 64 + lane];
        unsigned v5 = hlb[(size_t)p2.z * 64 + lane];
        unsigned v6 = hlb[(size_t)p3.x * 64 + lane];
        unsigned v7 = hlb[(size_t)p3.z * 64 + lane];
        float w0 = __int_as_float(p0.y), w1 = __int_as_float(p0.w);
        float w2 = __int_as_float(p1.y), w3 = __int_as_float(p1.w);
        float w4 = __int_as_float(p2.y), w5 = __int_as_float(p2.w);
        float w6 = __int_as_float(p3.y), w7 = __int_as_float(p3.w);
        acc.x += w0 * __uint_as_float(v0 << 16);
        acc.y += w0 * __uint_as_float(v0 & 0xffff0000u);
        acc.x += w1 * __uint_as_float(v1 << 16);
        acc.y += w1 * __uint_as_float(v1 & 0xffff0000u);
        acc.x += w2 * __uint_as_float(v2 << 16);
        acc.y += w2 * __uint_as_float(v2 & 0xffff0000u);
        acc.x += w3 * __uint_as_float(v3 << 16);
        acc.y += w3 * __uint_as_float(v3 & 0xffff0000u);
        acc.x += w4 * __uint_as_float(v4 << 16);
        acc.y += w4 * __uint_as_float(v4 & 0xffff0000u);
        acc.x += w5 * __uint_as_float(v5 << 16);
        acc.y += w5 * __uint_as_float(v5 & 0xffff0000u);
        acc.x += w6 * __uint_as_float(v6 << 16);
        acc.y += w6 * __uint_as_float(v6 & 0xffff0000u);
        acc.x += w7 * __uint_as_float(v7 << 16);
        acc.y += w7 * __uint_as_float(v7 & 0xffff0000u);
    }
    for (; e < end; ++e) {
        int2 c = csr[e];
        unsigned v = hlb[(size_t)c.x * 64 + lane];
        float w = __int_as_float(c.y);
        acc.x += w * __uint_as_float(v << 16);
        acc.y += w * __uint_as_float(v & 0xffff0000u);
    }
    ((float2*)out)[(size_t)node * 64 + lane] = acc;
}

extern "C" void kernel_launch(void* const* d_in, const int* in_sizes, int n_in,
                              void* d_out, int out_size, void* d_ws, size_t ws_size,
                              hipStream_t stream) {
    const float* h = (const float*)d_in[0];
    const float* W = (const float*)d_in[1];
    const float* b = (const float*)d_in[2];
    const int* edges = (const int*)d_in[3];

    const int n = in_sizes[0] / IN_DIM;   // 50000
    const int E = in_sizes[3] / 2;        // 800000
    const int nb = (n + 1023) / 1024;     // 49 scan blocks

    // workspace carve-up (float units, each region 2KB-aligned)
    size_t o = 0;
    auto carve = [&](size_t elems) {
        size_t cur = o;
        o += (elems + 511) & ~(size_t)511;
        return cur;
    };
    float* ws = (float*)d_ws;
    unsigned short* hlb = (unsigned short*)(ws + carve((size_t)n * 64));  // n*128 bf16
    int*   cnt     = (int*)(ws + carve(n));
    int*   off     = (int*)(ws + carve(n + 1));
    int*   cursor  = (int*)(ws + carve(n));
    float* degf    = ws + carve(n);
    int*   bsum    = (int*)(ws + carve(64));
    int*   bbase   = (int*)(ws + carve(64));
    int2*  csr     = (int2*)(ws + carve((size_t)E * 2));

    float* out = (float*)d_out;

    k_linear<<<(n + 127) / 128, 256, 0, stream>>>(h, W, b, hlb, n);
    k_zero_cnt<<<(n + 255) / 256, 256, 0, stream>>>(cnt, n);
    k_count<<<(E + 255) / 256, 256, 0, stream>>>(edges + E, cnt, E);
    k_scan1<<<nb, 1024, 0, stream>>>(cnt, off, bsum, n);
    k_scan2<<<1, 64, 0, stream>>>(bsum, bbase, off, nb, n);
    k_scan3<<<nb, 1024, 0, stream>>>(cnt, bbase, off, cursor, degf, n);
    k_fill<<<(E + 255) / 256, 256, 0, stream>>>(edges, degf, cursor, csr, E);
    k_agg<<<(n + 3) / 4, 256, 0, stream>>>(off, csr, degf,
                                           (const unsigned*)hlb, out, n);
}